// Round 18
// baseline (1624.592 us; speedup 1.0000x reference)
//
#include <hip/hip_runtime.h>
#include <stdint.h>

typedef _Float16 f16;
typedef _Float16 h2 __attribute__((ext_vector_type(2)));
typedef float f4 __attribute__((ext_vector_type(4)));

union F4H { f4 v; h2 h[4]; f16 s[8]; };

__device__ __forceinline__ float fdot2(h2 a, h2 b, float c) {
    return __builtin_amdgcn_fdot2(a, b, c, false);
}

// light barrier: LDS-ordering only (no vmcnt drain)
__device__ __forceinline__ void lbar() {
    __builtin_amdgcn_sched_barrier(0);
    asm volatile("s_waitcnt lgkmcnt(0)" ::: "memory");
    __builtin_amdgcn_s_barrier();
    __builtin_amdgcn_sched_barrier(0);
}

#define NB 64
#define NT 512
#define NH 256
#define NG 1024

// ---------------- workspace layout (r7 footprint) ----------------
static const size_t OFF_H0   = 0;           // h0 f16  [64][512][256]   16,777,216 B
static const size_t OFF_X1   = 16777216;    // x1 f16  [64*512][1024]   67,108,864 B
static const size_t OFF_H1   = 83886080;    // h1 f16  [64][512][256]   16,777,216 B
static const size_t OFF_PL0  = 100663296;   // packed Whh0 [32][1024] f4  524,288 B
static const size_t OFF_PL1  = 101187584;   // packed Whh1                524,288 B
static const size_t OFF_WIH1 = 101711872;   // packed Wih1 [32][1024] f4  524,288 B
static const size_t OFF_WX0  = 102236160;   // wx0 h2 [4][1024]            16,384 B
static const size_t OFF_B0C  = 102252544;   // bias0c f32 [1024]            4,096 B
static const size_t OFF_B1C  = 102256640;   // bias1c f32 [1024]            4,096 B
static const size_t OFF_WR1  = 102260736;   // wr1p f4 [32][128]           65,536 B
static const size_t OFF_MM   = 102326272;   // mmean f32 [64][256]         65,536 B
static const size_t OFF_M1S  = 102391808;   // m1sum f32 [64][128]         32,768 B
static const size_t OFF_HL   = 102424576;   // hh1last f32 (k4a, AFTER mega)
static const size_t OFF_FLG  = OFF_HL;      // flags alias hh1last (dead until k4a)

// ---------------- r11 column permutation ----------------
// Packed slot -> original gate-column. Thread t owns slots t and t+512:
//   slot t      (t=2u+c, c=0/1): col u + c*256      -> even: i_u, odd: f_u
//   slot 512+t  :                col 512 + u + c*256 -> even: g_u, odd: o_u
// So pair (2u,2u+1) holds {i,f,g,o}_u -> gate exchange = 2x shfl_xor(.,1),
// no gates[] LDS round-trip, one barrier per step.
__device__ __forceinline__ int permcol(int slot) {
    const int s = slot & 511;
    const int u = s >> 1, c = s & 1;
    return (slot >> 9) * 512 + u + c * 256;
}

// ---------------- merged packing kernel ----------------
__device__ __forceinline__ void packw(const float* src, f4* dst, int id)
{
    const int j = id >> 5;              // packed slot
    const int g = id & 31;
    const float* s = src + permcol(j) * 256 + g * 8;
    F4H u;
    #pragma unroll
    for (int i = 0; i < 8; ++i) u.s[i] = (f16)s[i];
    dst[g * 1024 + j] = u.v;
}

__global__ void pack_all(const float* __restrict__ Whh0, const float* __restrict__ Whh1,
                         const float* __restrict__ Wih1, const float* __restrict__ wih0,
                         const float* __restrict__ bih0, const float* __restrict__ bhh0,
                         const float* __restrict__ bih1, const float* __restrict__ bhh1,
                         const float* __restrict__ wr1,
                         f4* __restrict__ pl0, f4* __restrict__ pl1, f4* __restrict__ wih1p,
                         float* __restrict__ b0c, float* __restrict__ b1c,
                         h2* __restrict__ wx0p, f4* __restrict__ wr1p)
{
    const int id = blockIdx.x * 256 + threadIdx.x;   // 108544 tasks
    if (id < 32768) {
        packw(Whh0, pl0, id);
    } else if (id < 65536) {
        packw(Whh1, pl1, id - 32768);
    } else if (id < 98304) {
        packw(Wih1, wih1p, id - 65536);   // permuted rows -> x1 lands pre-permuted
    } else if (id < 99328) {
        const int j = id - 98304;
        const int pc = permcol(j);
        b0c[j] = bih0[pc] + bhh0[pc];
    } else if (id < 100352) {
        const int j = id - 99328;
        const int pc = permcol(j);
        b1c[j] = bih1[pc] + bhh1[pc];
    } else if (id < 104448) {
        const int q = id - 100352;
        const int p = q >> 10, j = q & 1023;
        const int pc = permcol(j);
        h2 v; v[0] = (f16)wih0[pc * 8 + 2 * p]; v[1] = (f16)wih0[pc * 8 + 2 * p + 1];
        wx0p[p * 1024 + j] = v;
    } else {
        const int q = id - 104448;
        const int g = q >> 7, o = q & 127;
        F4H u;
        #pragma unroll
        for (int i = 0; i < 8; ++i)
            u.s[i] = (o < 100) ? (f16)wr1[o * 256 + g * 8 + i] : (f16)0.f;
        wr1p[g * 128 + o] = u.v;
    }
}

// ---------------- mega-kernel: 3-stage pipeline, CH=4 ----------------
// r19 = r18 (verified: mega 1093, total 1155.1) with pipeline chunk halved
// again 8 -> 4. Lag (chain0 chunk + k2 chunk) ~11 -> ~7 steps. The chunk
// lever is quantitatively validated (16->8: predicted -16us, got -22us).
// Cost: role0 full-sync drain 128x (was 64x), k2 re-reads wih1p 4x
// (L2-resident; k2 has ~5x slack per window). Math bit-identical.
// k-split unchanged: 9 LDS + 11 reg-resident + 12 streamed (dist-2 dbuf);
// r17's latency rotations (x1-defer, prologue-across-barrier) kept.
#define DOT8(wa_, wb_, hh_) { F4H wa_u; wa_u.v = (wa_); F4H wb_u; wb_u.v = (wb_); F4H hh_u; hh_u.v = (hh_); \
    a0  = fdot2(wa_u.h[0], hh_u.h[0], a0 ); a1  = fdot2(wb_u.h[0], hh_u.h[0], a1 ); \
    a0b = fdot2(wa_u.h[1], hh_u.h[1], a0b); a1b = fdot2(wb_u.h[1], hh_u.h[1], a1b); \
    a0  = fdot2(wa_u.h[2], hh_u.h[2], a0 ); a1  = fdot2(wb_u.h[2], hh_u.h[2], a1 ); \
    a0b = fdot2(wa_u.h[3], hh_u.h[3], a0b); a1b = fdot2(wb_u.h[3], hh_u.h[3], a1b); }

#define STREAM_PHASES(HV) \
    _Pragma("unroll") \
    for (int p = 0; p < 6; ++p) { \
        if ((p & 1) == 0) { \
            DOT8(pA0[0], pA1[0], (HV)[20 + 2 * p]); \
            DOT8(pA0[1], pA1[1], (HV)[21 + 2 * p]); \
            if (p < 4) { \
                pA0[0] = str[(2 * (p + 2))     * 1024 + j0]; \
                pA1[0] = str[(2 * (p + 2))     * 1024 + j1]; \
                pA0[1] = str[(2 * (p + 2) + 1) * 1024 + j0]; \
                pA1[1] = str[(2 * (p + 2) + 1) * 1024 + j1]; \
            } \
        } else { \
            DOT8(pB0[0], pB1[0], (HV)[20 + 2 * p]); \
            DOT8(pB0[1], pB1[1], (HV)[21 + 2 * p]); \
            if (p < 4) { \
                pB0[0] = str[(2 * (p + 2))     * 1024 + j0]; \
                pB1[0] = str[(2 * (p + 2))     * 1024 + j1]; \
                pB0[1] = str[(2 * (p + 2) + 1) * 1024 + j0]; \
                pB1[1] = str[(2 * (p + 2) + 1) * 1024 + j1]; \
            } \
        } \
        DOT8(wrA[2 * p], wrB[2 * p], (HV)[9 + 2 * p]); \
        if (p < 5) DOT8(wrA[2 * p + 1], wrB[2 * p + 1], (HV)[10 + 2 * p]); \
    }

// rotated prologue refill: groups 0-3 for the NEXT step (pA/pB dead after
// STREAM_PHASES; issued pre-barrier so the loads fly across lbar)
#define STREAM_PROLOGUE() { \
    _Pragma("unroll") \
    for (int g = 0; g < 2; ++g) { pA0[g] = str[g * 1024 + j0]; pA1[g] = str[g * 1024 + j1]; } \
    _Pragma("unroll") \
    for (int g = 0; g < 2; ++g) { pB0[g] = str[(2 + g) * 1024 + j0]; pB1[g] = str[(2 + g) * 1024 + j1]; } }

__global__ __launch_bounds__(512, 2)
void mega(const float* __restrict__ x,
          const f4* __restrict__ pl0, const f4* __restrict__ pl1,
          const f4* __restrict__ wih1p,
          const float* __restrict__ b0c, const float* __restrict__ b1c,
          const h2* __restrict__ wx0p,
          f16* __restrict__ h0, f16* __restrict__ x1, f16* __restrict__ h1,
          float* __restrict__ mmean, unsigned int* __restrict__ flags)
{
    __shared__ f4 wlds[9 * 1024];                 // 144 KB (chain roles)
    __shared__ __align__(16) f16 hbuf[2][256];    // 1 KB double-buffered h
    __shared__ __align__(16) h2 xsh[512 * 4];     // 8 KB: role0 x frags; role1 h0 tile
    // total 156,672 B < 160 KiB -> 1 WG/CU

    const int t = threadIdx.x;
    const int bid = blockIdx.x;
    const int role = bid >> 6;
    const int b = bid & 63;
    const int j0 = t, j1 = t + 512;

    if (role == 0) {
        // =================== layer-0 chain (producer) ===================
        const f4* pack = pl0;
        #pragma unroll
        for (int i = 0; i < 18; ++i) wlds[t + 512 * i] = pack[t + 512 * i];
        f4 wrA[11], wrB[11];
        #pragma unroll
        for (int g = 0; g < 11; ++g) {
            wrA[g] = pack[(9 + g) * 1024 + j0];
            wrB[g] = pack[(9 + g) * 1024 + j1];
        }
        #pragma unroll
        for (int g = 0; g < 11; ++g)
            asm volatile("" : "+v"(wrA[g]), "+v"(wrB[g]));
        const f4* str = pack + 20 * 1024;

        const float bc0 = b0c[j0], bc1 = b0c[j1];
        h2 wxA[4], wxB[4];
        #pragma unroll
        for (int p = 0; p < 4; ++p) { wxA[p] = wx0p[p * 1024 + j0]; wxB[p] = wx0p[p * 1024 + j1]; }
        const float* xb = x + ((size_t)b * NT + t) * 8;
        #pragma unroll
        for (int p = 0; p < 4; ++p) {
            h2 v; v[0] = (f16)xb[2 * p]; v[1] = (f16)xb[2 * p + 1];
            xsh[t * 4 + p] = v;
        }
        if (t < 32) { f4 zz = {0.f, 0.f, 0.f, 0.f}; ((f4*)hbuf)[t] = zz; }  // zero hbuf[0]
        float cst = 0.f;
        __syncthreads();

        f16* houtb = h0 + (size_t)b * NT * NH;
        unsigned int* myfl = flags + b * 16;
        const int u = t >> 1, odd = t & 1;

        f4 pA0[2], pA1[2], pB0[2], pB1[2];
        STREAM_PROLOGUE()

        #pragma unroll 1
        for (int tt = 0; tt < NT; ++tt) {
            float a0 = bc0, a1 = bc1, a0b = 0.f, a1b = 0.f;
            #pragma unroll
            for (int p = 0; p < 4; ++p) {
                h2 xv = xsh[tt * 4 + p];
                a0 = fdot2(wxA[p], xv, a0);
                a1 = fdot2(wxB[p], xv, a1);
            }

            const f4* hv4 = ((const f4*)hbuf) + (tt & 1) * 32;
            #pragma unroll
            for (int i = 0; i < 9; ++i) DOT8(wlds[i * 1024 + j0], wlds[i * 1024 + j1], hv4[i]);
            STREAM_PHASES(hv4)

            // ---- in-register gates via pair exchange (no LDS, no extra barrier)
            float av = a0 + a0b;                       // even: i_u   odd: f_u
            float bv = a1 + a1b;                       // even: g_u   odd: o_u
            float fa = __shfl_xor(av, 1, 64);
            float fb = __shfl_xor(bv, 1, 64);
            float gi = odd ? fa : av;
            float gf = odd ? av : fa;
            float gg = odd ? fb : bv;
            float go = odd ? bv : fb;
            float si = 1.f / (1.f + __expf(-gi));
            float sf = 1.f / (1.f + __expf(-gf));
            float so = 1.f / (1.f + __expf(-go));
            float tg = 1.f - 2.f / (__expf(2.f * gg) + 1.f);
            cst = sf * cst + si * tg;
            float th = 1.f - 2.f / (__expf(2.f * cst) + 1.f);
            float hvl = so * th;
            if (!odd) {
                hbuf[(tt & 1) ^ 1][u] = (f16)hvl;
                houtb[(size_t)tt * NH + u] = (f16)hvl;
            }
            STREAM_PROLOGUE()   // next-step groups 0-3, in flight across barrier
            if (((tt + 1) & 3) == 0) {
                __syncthreads();   // full: drains h0 stores before release
                if (t == 0)
                    __hip_atomic_store(myfl, (unsigned)(tt + 1),
                                       __ATOMIC_RELEASE, __HIP_MEMORY_SCOPE_AGENT);
            } else {
                lbar();            // LDS-only: new h visible
            }
        }
    } else if (role == 1) {
        // ============ chunked k2 GEMM, 4-row sub-chunks ============
        const float bc0 = b1c[j0], bc1 = b1c[j1];
        const f16* h0b = h0 + (size_t)b * NT * NH;
        f16* x1b = x1 + (size_t)b * NT * NG;
        const unsigned int* pfl = flags + b * 16;
        unsigned int* myfl = flags + 1024 + b * 16;
        f16* hrows = (f16*)xsh;    // [4][256] f16 = 2 KB
        bool dead = false;

        #pragma unroll 1
        for (int c = 0; c < 128; ++c) {
            if (t < 64 && !dead) {
                unsigned int guard = 0;
                while (__hip_atomic_load(pfl, __ATOMIC_ACQUIRE, __HIP_MEMORY_SCOPE_AGENT)
                       < (unsigned)((c + 1) * 4)) {
                    __builtin_amdgcn_s_sleep(8);
                    if (++guard > (1u << 17)) { dead = true; break; }
                }
            }
            __syncthreads();
            if (t < 128) {
                const int rr = t >> 5, cc = t & 31;
                ((f4*)hrows)[t] = ((const f4*)(h0b + (size_t)(c * 4 + rr) * NH))[cc];
            }
            __syncthreads();

            float acc0[4], acc1[4];
            #pragma unroll
            for (int r = 0; r < 4; ++r) { acc0[r] = bc0; acc1[r] = bc1; }

            f4 w0 = wih1p[j0], w1 = wih1p[j1];
            #pragma unroll 1
            for (int g = 0; g < 32; ++g) {
                f4 n0 = w0, n1 = w1;
                if (g < 31) { n0 = wih1p[(g + 1) * 1024 + j0]; n1 = wih1p[(g + 1) * 1024 + j1]; }
                F4H W0; W0.v = w0; F4H W1; W1.v = w1;
                #pragma unroll
                for (int r = 0; r < 4; ++r) {
                    F4H H; H.v = ((const f4*)hrows)[r * 32 + g];
                    acc0[r] = fdot2(W0.h[0], H.h[0], acc0[r]);
                    acc0[r] = fdot2(W0.h[1], H.h[1], acc0[r]);
                    acc0[r] = fdot2(W0.h[2], H.h[2], acc0[r]);
                    acc0[r] = fdot2(W0.h[3], H.h[3], acc0[r]);
                    acc1[r] = fdot2(W1.h[0], H.h[0], acc1[r]);
                    acc1[r] = fdot2(W1.h[1], H.h[1], acc1[r]);
                    acc1[r] = fdot2(W1.h[2], H.h[2], acc1[r]);
                    acc1[r] = fdot2(W1.h[3], H.h[3], acc1[r]);
                }
                w0 = n0; w1 = n1;
            }
            #pragma unroll
            for (int r = 0; r < 4; ++r) {
                x1b[(size_t)(c * 4 + r) * NG + j0] = (f16)acc0[r];
                x1b[(size_t)(c * 4 + r) * NG + j1] = (f16)acc1[r];
            }
            __syncthreads();
            if (t == 0) __hip_atomic_store(myfl, (unsigned)(c + 1),
                                           __ATOMIC_RELEASE, __HIP_MEMORY_SCOPE_AGENT);
        }
    } else {
        // =================== layer-1 chain (consumer of x1) ===================
        const f4* pack = pl1;
        #pragma unroll
        for (int i = 0; i < 18; ++i) wlds[t + 512 * i] = pack[t + 512 * i];
        f4 wrA[11], wrB[11];
        #pragma unroll
        for (int g = 0; g < 11; ++g) {
            wrA[g] = pack[(9 + g) * 1024 + j0];
            wrB[g] = pack[(9 + g) * 1024 + j1];
        }
        #pragma unroll
        for (int g = 0; g < 11; ++g)
            asm volatile("" : "+v"(wrA[g]), "+v"(wrB[g]));
        const f4* str = pack + 20 * 1024;

        if (t < 32) { f4 zz = {0.f, 0.f, 0.f, 0.f}; ((f4*)hbuf)[t] = zz; }
        float cst = 0.f, hsum = 0.f;
        __syncthreads();
        const f16* x1b = x1 + (size_t)b * NT * NG;
        f16* houtb = h1 + (size_t)b * NT * NH;
        const unsigned int* pfl = flags + 1024 + b * 16;
        bool dead = false;
        const int u = t >> 1, odd = t & 1;

        f4 pA0[2], pA1[2], pB0[2], pB1[2];
        STREAM_PROLOGUE()

        #pragma unroll 1
        for (int tt = 0; tt < NT; ++tt) {
            if ((tt & 3) == 0) {                  // chunk-grained acquire, one wave spins
                if (t < 64 && !dead) {
                    unsigned int guard = 0;
                    while (__hip_atomic_load(pfl, __ATOMIC_ACQUIRE, __HIP_MEMORY_SCOPE_AGENT)
                           < (unsigned)((tt >> 2) + 1)) {
                        __builtin_amdgcn_s_sleep(8);
                        if (++guard > (1u << 17)) { dead = true; break; }
                    }
                }
                __syncthreads();
            }

            // x1 load issued here, consumed AFTER all dots (latency hidden)
            const f16* xr = x1b + (size_t)tt * NG;
            float x1v0 = (float)xr[j0];
            float x1v1 = (float)xr[j1];
            float a0 = 0.f, a1 = 0.f, a0b = 0.f, a1b = 0.f;

            const f4* hv4 = ((const f4*)hbuf) + (tt & 1) * 32;
            #pragma unroll
            for (int i = 0; i < 9; ++i) DOT8(wlds[i * 1024 + j0], wlds[i * 1024 + j1], hv4[i]);
            STREAM_PHASES(hv4)

            float av = a0 + a0b + x1v0;
            float bv = a1 + a1b + x1v1;
            float fa = __shfl_xor(av, 1, 64);
            float fb = __shfl_xor(bv, 1, 64);
            float gi = odd ? fa : av;
            float gf = odd ? av : fa;
            float gg = odd ? fb : bv;
            float go = odd ? bv : fb;
            float si = 1.f / (1.f + __expf(-gi));
            float sf = 1.f / (1.f + __expf(-gf));
            float so = 1.f / (1.f + __expf(-go));
            float tg = 1.f - 2.f / (__expf(2.f * gg) + 1.f);
            cst = sf * cst + si * tg;
            float th = 1.f - 2.f / (__expf(2.f * cst) + 1.f);
            float hvl = so * th;
            if (!odd) {
                hbuf[(tt & 1) ^ 1][u] = (f16)hvl;
                houtb[(size_t)tt * NH + u] = (f16)hvl;
                hsum += hvl;
            }
            STREAM_PROLOGUE()   // next-step groups 0-3, in flight across barrier
            lbar();             // one light barrier per step
        }
        if (!odd) mmean[b * NH + u] = hsum * (1.f / 512.f);
    }
}

// ---------------- K4a (proven) ----------------
__global__ __launch_bounds__(256)
void k4a(const f16* __restrict__ h1, const float* __restrict__ mmean,
         const float* __restrict__ Wl1, const float* __restrict__ b1,
         const f4* __restrict__ wr1p, float* __restrict__ m1sum,
         float* __restrict__ hh1last)
{
    __shared__ __align__(16) f16 ash[64 * 256];
    __shared__ float msh[256];
    __shared__ float mbase[128];
    __shared__ float red[256];
    const int l = threadIdx.x;
    const int b = blockIdx.x >> 3;
    const int ch = blockIdx.x & 7;

    const f4* src = (const f4*)(h1 + ((size_t)b * 512 + ch * 64) * 256);
    f4* dst = (f4*)ash;
    #pragma unroll
    for (int i = 0; i < 8; ++i) dst[l + 256 * i] = src[l + 256 * i];
    msh[l] = mmean[b * 256 + l];
    __syncthreads();

    if (l < 128) {
        float acc = 0.f;
        if (l < 100) {
            acc = b1[l];
            const float* wrow = Wl1 + l * 256;
            for (int j = 0; j < 256; ++j) acc += msh[j] * wrow[j];
        }
        mbase[l] = acc;
    }
    __syncthreads();

    const int o = l & 127;
    const int th = l >> 7;
    float sumloc = 0.f;
    float last = 0.f;
    #pragma unroll 1
    for (int it = 0; it < 32; ++it) {
        const int tloc = it * 2 + th;
        float acc = mbase[o];
        const f4* arow = (const f4*)(ash + tloc * 256);
        #pragma unroll
        for (int u = 0; u < 32; ++u) {
            F4H av; av.v = arow[u];
            F4H wv; wv.v = wr1p[u * 128 + o];
            #pragma unroll
            for (int p = 0; p < 4; ++p) acc = fdot2(av.h[p], wv.h[p], acc);
        }
        float e = acc > 0.f ? acc : (__expf(acc) - 1.f);
        sumloc += e;
        if (tloc == 63) last = e;
    }
    red[l] = sumloc;
    __syncthreads();
    if (l < 128) {
        float s = red[l] + red[l + 128];
        if (l < 100) atomicAdd(m1sum + b * 128 + l, s);
    }
    if (ch == 7 && th == 1) hh1last[b * 128 + o] = last;
}

// ---------------- K4b: final head (proven) ----------------
__global__ __launch_bounds__(128)
void k4b(const float* __restrict__ m1sum, const float* __restrict__ hh1last,
         const float* __restrict__ Wl2, const float* __restrict__ Wr2,
         const float* __restrict__ b2,
         const float* __restrict__ Wfc1, const float* __restrict__ bfc1,
         const float* __restrict__ Wfc2, const float* __restrict__ bfc2,
         float* __restrict__ out)
{
    __shared__ float m1s[128];
    __shared__ float hl[128];
    __shared__ float s[128];
    __shared__ float zsh[512];
    const int b = blockIdx.x;
    const int l = threadIdx.x;

    m1s[l] = m1sum[b * 128 + l] * (1.f / 512.f);
    hl[l] = hh1last[b * 128 + l];
    __syncthreads();

    {
        float acc = b2[l];
        const float* wl2r = Wl2 + l * 100;
        const float* wr2r = Wr2 + l * 100;
        for (int j = 0; j < 100; ++j) acc += m1s[j] * wl2r[j] + hl[j] * wr2r[j];
        s[l] = acc;
    }
    __syncthreads();

    #pragma unroll 1
    for (int i = 0; i < 4; ++i) {
        const int idx = l + 128 * i;
        const int k = idx >> 6, o = idx & 63;
        const float* w = Wfc1 + (size_t)(k * 64 + o) * 128;
        float a = bfc1[k * 64 + o];
        for (int d = 0; d < 128; ++d) a += s[d] * w[d];
        zsh[idx] = a > 0.f ? a : 0.f;
    }
    __syncthreads();

    #pragma unroll 1
    for (int i = 0; i < 2; ++i) {
        const int idx = l + 128 * i;
        if (idx < 192) {
            const int k = idx / 24, p = idx % 24;
            const float* w = Wfc2 + (size_t)(k * 24 + p) * 64;
            float a = bfc2[k * 24 + p];
            const float* z = zsh + k * 64;
            for (int d = 0; d < 64; ++d) a += z[d] * w[d];
            out[(size_t)(k * 64 + b) * 24 + p] = a;
        }
    }
}

// ---------------- launch ----------------
extern "C" void kernel_launch(void* const* d_in, const int* in_sizes, int n_in,
                              void* d_out, int out_size, void* d_ws, size_t ws_size,
                              hipStream_t stream)
{
    const float* x    = (const float*)d_in[0];
    const float* Wih0 = (const float*)d_in[1];
    const float* Whh0 = (const float*)d_in[2];
    const float* bih0 = (const float*)d_in[3];
    const float* bhh0 = (const float*)d_in[4];
    const float* Wih1 = (const float*)d_in[5];
    const float* Whh1 = (const float*)d_in[6];
    const float* bih1 = (const float*)d_in[7];
    const float* bhh1 = (const float*)d_in[8];
    const float* Wl1  = (const float*)d_in[9];
    const float* Wr1  = (const float*)d_in[10];
    const float* b1   = (const float*)d_in[11];
    const float* Wl2  = (const float*)d_in[12];
    const float* Wr2  = (const float*)d_in[13];
    const float* b2   = (const float*)d_in[14];
    const float* Wfc1 = (const float*)d_in[15];
    const float* bfc1 = (const float*)d_in[16];
    const float* Wfc2 = (const float*)d_in[17];
    const float* bfc2 = (const float*)d_in[18];

    char* ws = (char*)d_ws;
    f16*   h0f   = (f16*)(ws + OFF_H0);
    f16*   x1f   = (f16*)(ws + OFF_X1);
    f16*   h1f   = (f16*)(ws + OFF_H1);
    f4*    pl0   = (f4*)(ws + OFF_PL0);
    f4*    pl1   = (f4*)(ws + OFF_PL1);
    f4*    wih1p = (f4*)(ws + OFF_WIH1);
    h2*    wx0p  = (h2*)(ws + OFF_WX0);
    float* b0c   = (float*)(ws + OFF_B0C);
    float* b1c   = (float*)(ws + OFF_B1C);
    f4*    wr1p  = (f4*)(ws + OFF_WR1);
    float* mm    = (float*)(ws + OFF_MM);
    float* m1s   = (float*)(ws + OFF_M1S);
    float* hhl   = (float*)(ws + OFF_HL);
    unsigned int* flg = (unsigned int*)(ws + OFF_FLG);

    pack_all<<<424, 256, 0, stream>>>(Whh0, Whh1, Wih1, Wih0,
                                      bih0, bhh0, bih1, bhh1, Wr1,
                                      pl0, pl1, wih1p, b0c, b1c, wx0p, wr1p);
    hipMemsetAsync(m1s, 0, 64 * 128 * sizeof(float), stream);
    hipMemsetAsync(flg, 0, 8192, stream);

    // pipelined chain0 -> k2 -> chain1, one launch, 192 co-resident WGs
    mega<<<192, 512, 0, stream>>>(x, pl0, pl1, wih1p, b0c, b1c, wx0p,
                                  h0f, x1f, h1f, mm, flg);

    k4a<<<512, 256, 0, stream>>>(h1f, mm, Wl1, b1, wr1p, m1s, hhl);
    k4b<<<64, 128, 0, stream>>>(m1s, hhl, Wl2, Wr2, b2, Wfc1, bfc1, Wfc2, bfc2, (float*)d_out);
}

// Round 19
// 1153.831 us; speedup vs baseline: 1.4080x; 1.4080x over previous
//
#include <hip/hip_runtime.h>
#include <stdint.h>

typedef _Float16 f16;
typedef _Float16 h2 __attribute__((ext_vector_type(2)));
typedef float f4 __attribute__((ext_vector_type(4)));

union F4H { f4 v; h2 h[4]; f16 s[8]; };

__device__ __forceinline__ float fdot2(h2 a, h2 b, float c) {
    return __builtin_amdgcn_fdot2(a, b, c, false);
}

// light barrier: LDS-ordering only (no vmcnt drain)
__device__ __forceinline__ void lbar() {
    __builtin_amdgcn_sched_barrier(0);
    asm volatile("s_waitcnt lgkmcnt(0)" ::: "memory");
    __builtin_amdgcn_s_barrier();
    __builtin_amdgcn_sched_barrier(0);
}

#define NB 64
#define NT 512
#define NH 256
#define NG 1024

// ---------------- workspace layout (r7 footprint) ----------------
static const size_t OFF_H0   = 0;           // h0 f16  [64][512][256]   16,777,216 B
static const size_t OFF_X1   = 16777216;    // x1 f16  [64*512][1024]   67,108,864 B
static const size_t OFF_H1   = 83886080;    // h1 f16  [64][512][256]   16,777,216 B
static const size_t OFF_PL0  = 100663296;   // packed Whh0 [32][1024] f4  524,288 B
static const size_t OFF_PL1  = 101187584;   // packed Whh1                524,288 B
static const size_t OFF_WIH1 = 101711872;   // packed Wih1 [32][1024] f4  524,288 B
static const size_t OFF_WX0  = 102236160;   // wx0 h2 [4][1024]            16,384 B
static const size_t OFF_B0C  = 102252544;   // bias0c f32 [1024]            4,096 B
static const size_t OFF_B1C  = 102256640;   // bias1c f32 [1024]            4,096 B
static const size_t OFF_WR1  = 102260736;   // wr1p f4 [32][128]           65,536 B
static const size_t OFF_MM   = 102326272;   // mmean f32 [64][256]         65,536 B
static const size_t OFF_M1S  = 102391808;   // m1sum f32 [64][128]         32,768 B
static const size_t OFF_HL   = 102424576;   // hh1last f32 (k4a, AFTER mega)
static const size_t OFF_FLG  = OFF_HL;      // flags alias hh1last (dead until k4a)

// ---------------- r11 column permutation ----------------
// Packed slot -> original gate-column. Thread t owns slots t and t+512:
//   slot t      (t=2u+c, c=0/1): col u + c*256      -> even: i_u, odd: f_u
//   slot 512+t  :                col 512 + u + c*256 -> even: g_u, odd: o_u
// So pair (2u,2u+1) holds {i,f,g,o}_u -> gate exchange = 2x shfl_xor(.,1),
// no gates[] LDS round-trip, one barrier per step.
__device__ __forceinline__ int permcol(int slot) {
    const int s = slot & 511;
    const int u = s >> 1, c = s & 1;
    return (slot >> 9) * 512 + u + c * 256;
}

// ---------------- merged packing kernel ----------------
__device__ __forceinline__ void packw(const float* src, f4* dst, int id)
{
    const int j = id >> 5;              // packed slot
    const int g = id & 31;
    const float* s = src + permcol(j) * 256 + g * 8;
    F4H u;
    #pragma unroll
    for (int i = 0; i < 8; ++i) u.s[i] = (f16)s[i];
    dst[g * 1024 + j] = u.v;
}

__global__ void pack_all(const float* __restrict__ Whh0, const float* __restrict__ Whh1,
                         const float* __restrict__ Wih1, const float* __restrict__ wih0,
                         const float* __restrict__ bih0, const float* __restrict__ bhh0,
                         const float* __restrict__ bih1, const float* __restrict__ bhh1,
                         const float* __restrict__ wr1,
                         f4* __restrict__ pl0, f4* __restrict__ pl1, f4* __restrict__ wih1p,
                         float* __restrict__ b0c, float* __restrict__ b1c,
                         h2* __restrict__ wx0p, f4* __restrict__ wr1p)
{
    const int id = blockIdx.x * 256 + threadIdx.x;   // 108544 tasks
    if (id < 32768) {
        packw(Whh0, pl0, id);
    } else if (id < 65536) {
        packw(Whh1, pl1, id - 32768);
    } else if (id < 98304) {
        packw(Wih1, wih1p, id - 65536);   // permuted rows -> x1 lands pre-permuted
    } else if (id < 99328) {
        const int j = id - 98304;
        const int pc = permcol(j);
        b0c[j] = bih0[pc] + bhh0[pc];
    } else if (id < 100352) {
        const int j = id - 99328;
        const int pc = permcol(j);
        b1c[j] = bih1[pc] + bhh1[pc];
    } else if (id < 104448) {
        const int q = id - 100352;
        const int p = q >> 10, j = q & 1023;
        const int pc = permcol(j);
        h2 v; v[0] = (f16)wih0[pc * 8 + 2 * p]; v[1] = (f16)wih0[pc * 8 + 2 * p + 1];
        wx0p[p * 1024 + j] = v;
    } else {
        const int q = id - 104448;
        const int g = q >> 7, o = q & 127;
        F4H u;
        #pragma unroll
        for (int i = 0; i < 8; ++i)
            u.s[i] = (o < 100) ? (f16)wr1[o * 256 + g * 8 + i] : (f16)0.f;
        wr1p[g * 128 + o] = u.v;
    }
}

// ---------------- mega-kernel: 3-stage pipeline, CH=8 ----------------
// r20 = EXACT revert to r18, the verified session optimum (mega 1093,
// total 1155.1). Chunk ladder measured: CH=16: 1163, CH=8: 1155,
// CH=4: 1625 (sync-dominated cliff — k2 sub-chunk service latency and
// producer jitter don't shrink with work size). CH=8 is the minimum.
// Structure: 9 LDS + 11 reg-resident + 12 streamed (dist-2 dbuf);
// x1-defer + prologue-across-barrier latency rotations; pair-exchange
// gates; 1 light barrier/step; full sync only at chunk release.
#define DOT8(wa_, wb_, hh_) { F4H wa_u; wa_u.v = (wa_); F4H wb_u; wb_u.v = (wb_); F4H hh_u; hh_u.v = (hh_); \
    a0  = fdot2(wa_u.h[0], hh_u.h[0], a0 ); a1  = fdot2(wb_u.h[0], hh_u.h[0], a1 ); \
    a0b = fdot2(wa_u.h[1], hh_u.h[1], a0b); a1b = fdot2(wb_u.h[1], hh_u.h[1], a1b); \
    a0  = fdot2(wa_u.h[2], hh_u.h[2], a0 ); a1  = fdot2(wb_u.h[2], hh_u.h[2], a1 ); \
    a0b = fdot2(wa_u.h[3], hh_u.h[3], a0b); a1b = fdot2(wb_u.h[3], hh_u.h[3], a1b); }

#define STREAM_PHASES(HV) \
    _Pragma("unroll") \
    for (int p = 0; p < 6; ++p) { \
        if ((p & 1) == 0) { \
            DOT8(pA0[0], pA1[0], (HV)[20 + 2 * p]); \
            DOT8(pA0[1], pA1[1], (HV)[21 + 2 * p]); \
            if (p < 4) { \
                pA0[0] = str[(2 * (p + 2))     * 1024 + j0]; \
                pA1[0] = str[(2 * (p + 2))     * 1024 + j1]; \
                pA0[1] = str[(2 * (p + 2) + 1) * 1024 + j0]; \
                pA1[1] = str[(2 * (p + 2) + 1) * 1024 + j1]; \
            } \
        } else { \
            DOT8(pB0[0], pB1[0], (HV)[20 + 2 * p]); \
            DOT8(pB0[1], pB1[1], (HV)[21 + 2 * p]); \
            if (p < 4) { \
                pB0[0] = str[(2 * (p + 2))     * 1024 + j0]; \
                pB1[0] = str[(2 * (p + 2))     * 1024 + j1]; \
                pB0[1] = str[(2 * (p + 2) + 1) * 1024 + j0]; \
                pB1[1] = str[(2 * (p + 2) + 1) * 1024 + j1]; \
            } \
        } \
        DOT8(wrA[2 * p], wrB[2 * p], (HV)[9 + 2 * p]); \
        if (p < 5) DOT8(wrA[2 * p + 1], wrB[2 * p + 1], (HV)[10 + 2 * p]); \
    }

// rotated prologue refill: groups 0-3 for the NEXT step (pA/pB dead after
// STREAM_PHASES; issued pre-barrier so the loads fly across lbar)
#define STREAM_PROLOGUE() { \
    _Pragma("unroll") \
    for (int g = 0; g < 2; ++g) { pA0[g] = str[g * 1024 + j0]; pA1[g] = str[g * 1024 + j1]; } \
    _Pragma("unroll") \
    for (int g = 0; g < 2; ++g) { pB0[g] = str[(2 + g) * 1024 + j0]; pB1[g] = str[(2 + g) * 1024 + j1]; } }

__global__ __launch_bounds__(512, 2)
void mega(const float* __restrict__ x,
          const f4* __restrict__ pl0, const f4* __restrict__ pl1,
          const f4* __restrict__ wih1p,
          const float* __restrict__ b0c, const float* __restrict__ b1c,
          const h2* __restrict__ wx0p,
          f16* __restrict__ h0, f16* __restrict__ x1, f16* __restrict__ h1,
          float* __restrict__ mmean, unsigned int* __restrict__ flags)
{
    __shared__ f4 wlds[9 * 1024];                 // 144 KB (chain roles)
    __shared__ __align__(16) f16 hbuf[2][256];    // 1 KB double-buffered h
    __shared__ __align__(16) h2 xsh[512 * 4];     // 8 KB: role0 x frags; role1 h0 tile
    // total 156,672 B < 160 KiB -> 1 WG/CU

    const int t = threadIdx.x;
    const int bid = blockIdx.x;
    const int role = bid >> 6;
    const int b = bid & 63;
    const int j0 = t, j1 = t + 512;

    if (role == 0) {
        // =================== layer-0 chain (producer) ===================
        const f4* pack = pl0;
        #pragma unroll
        for (int i = 0; i < 18; ++i) wlds[t + 512 * i] = pack[t + 512 * i];
        f4 wrA[11], wrB[11];
        #pragma unroll
        for (int g = 0; g < 11; ++g) {
            wrA[g] = pack[(9 + g) * 1024 + j0];
            wrB[g] = pack[(9 + g) * 1024 + j1];
        }
        #pragma unroll
        for (int g = 0; g < 11; ++g)
            asm volatile("" : "+v"(wrA[g]), "+v"(wrB[g]));
        const f4* str = pack + 20 * 1024;

        const float bc0 = b0c[j0], bc1 = b0c[j1];
        h2 wxA[4], wxB[4];
        #pragma unroll
        for (int p = 0; p < 4; ++p) { wxA[p] = wx0p[p * 1024 + j0]; wxB[p] = wx0p[p * 1024 + j1]; }
        const float* xb = x + ((size_t)b * NT + t) * 8;
        #pragma unroll
        for (int p = 0; p < 4; ++p) {
            h2 v; v[0] = (f16)xb[2 * p]; v[1] = (f16)xb[2 * p + 1];
            xsh[t * 4 + p] = v;
        }
        if (t < 32) { f4 zz = {0.f, 0.f, 0.f, 0.f}; ((f4*)hbuf)[t] = zz; }  // zero hbuf[0]
        float cst = 0.f;
        __syncthreads();

        f16* houtb = h0 + (size_t)b * NT * NH;
        unsigned int* myfl = flags + b * 16;
        const int u = t >> 1, odd = t & 1;

        f4 pA0[2], pA1[2], pB0[2], pB1[2];
        STREAM_PROLOGUE()

        #pragma unroll 1
        for (int tt = 0; tt < NT; ++tt) {
            float a0 = bc0, a1 = bc1, a0b = 0.f, a1b = 0.f;
            #pragma unroll
            for (int p = 0; p < 4; ++p) {
                h2 xv = xsh[tt * 4 + p];
                a0 = fdot2(wxA[p], xv, a0);
                a1 = fdot2(wxB[p], xv, a1);
            }

            const f4* hv4 = ((const f4*)hbuf) + (tt & 1) * 32;
            #pragma unroll
            for (int i = 0; i < 9; ++i) DOT8(wlds[i * 1024 + j0], wlds[i * 1024 + j1], hv4[i]);
            STREAM_PHASES(hv4)

            // ---- in-register gates via pair exchange (no LDS, no extra barrier)
            float av = a0 + a0b;                       // even: i_u   odd: f_u
            float bv = a1 + a1b;                       // even: g_u   odd: o_u
            float fa = __shfl_xor(av, 1, 64);
            float fb = __shfl_xor(bv, 1, 64);
            float gi = odd ? fa : av;
            float gf = odd ? av : fa;
            float gg = odd ? fb : bv;
            float go = odd ? bv : fb;
            float si = 1.f / (1.f + __expf(-gi));
            float sf = 1.f / (1.f + __expf(-gf));
            float so = 1.f / (1.f + __expf(-go));
            float tg = 1.f - 2.f / (__expf(2.f * gg) + 1.f);
            cst = sf * cst + si * tg;
            float th = 1.f - 2.f / (__expf(2.f * cst) + 1.f);
            float hvl = so * th;
            if (!odd) {
                hbuf[(tt & 1) ^ 1][u] = (f16)hvl;
                houtb[(size_t)tt * NH + u] = (f16)hvl;
            }
            STREAM_PROLOGUE()   // next-step groups 0-3, in flight across barrier
            if (((tt + 1) & 7) == 0) {
                __syncthreads();   // full: drains h0 stores before release
                if (t == 0)
                    __hip_atomic_store(myfl, (unsigned)(tt + 1),
                                       __ATOMIC_RELEASE, __HIP_MEMORY_SCOPE_AGENT);
            } else {
                lbar();            // LDS-only: new h visible
            }
        }
    } else if (role == 1) {
        // ============ chunked k2 GEMM, 8-row sub-chunks ============
        const float bc0 = b1c[j0], bc1 = b1c[j1];
        const f16* h0b = h0 + (size_t)b * NT * NH;
        f16* x1b = x1 + (size_t)b * NT * NG;
        const unsigned int* pfl = flags + b * 16;
        unsigned int* myfl = flags + 1024 + b * 16;
        f16* hrows = (f16*)xsh;    // [8][256] f16 = 4 KB
        bool dead = false;

        #pragma unroll 1
        for (int c = 0; c < 64; ++c) {
            if (t < 64 && !dead) {
                unsigned int guard = 0;
                while (__hip_atomic_load(pfl, __ATOMIC_ACQUIRE, __HIP_MEMORY_SCOPE_AGENT)
                       < (unsigned)((c + 1) * 8)) {
                    __builtin_amdgcn_s_sleep(8);
                    if (++guard > (1u << 16)) { dead = true; break; }
                }
            }
            __syncthreads();
            if (t < 256) {
                const int rr = t >> 5, cc = t & 31;
                ((f4*)hrows)[t] = ((const f4*)(h0b + (size_t)(c * 8 + rr) * NH))[cc];
            }
            __syncthreads();

            float acc0[8], acc1[8];
            #pragma unroll
            for (int r = 0; r < 8; ++r) { acc0[r] = bc0; acc1[r] = bc1; }

            f4 w0 = wih1p[j0], w1 = wih1p[j1];
            #pragma unroll 1
            for (int g = 0; g < 32; ++g) {
                f4 n0 = w0, n1 = w1;
                if (g < 31) { n0 = wih1p[(g + 1) * 1024 + j0]; n1 = wih1p[(g + 1) * 1024 + j1]; }
                F4H W0; W0.v = w0; F4H W1; W1.v = w1;
                #pragma unroll
                for (int r = 0; r < 8; ++r) {
                    F4H H; H.v = ((const f4*)hrows)[r * 32 + g];
                    acc0[r] = fdot2(W0.h[0], H.h[0], acc0[r]);
                    acc0[r] = fdot2(W0.h[1], H.h[1], acc0[r]);
                    acc0[r] = fdot2(W0.h[2], H.h[2], acc0[r]);
                    acc0[r] = fdot2(W0.h[3], H.h[3], acc0[r]);
                    acc1[r] = fdot2(W1.h[0], H.h[0], acc1[r]);
                    acc1[r] = fdot2(W1.h[1], H.h[1], acc1[r]);
                    acc1[r] = fdot2(W1.h[2], H.h[2], acc1[r]);
                    acc1[r] = fdot2(W1.h[3], H.h[3], acc1[r]);
                }
                w0 = n0; w1 = n1;
            }
            #pragma unroll
            for (int r = 0; r < 8; ++r) {
                x1b[(size_t)(c * 8 + r) * NG + j0] = (f16)acc0[r];
                x1b[(size_t)(c * 8 + r) * NG + j1] = (f16)acc1[r];
            }
            __syncthreads();
            if (t == 0) __hip_atomic_store(myfl, (unsigned)(c + 1),
                                           __ATOMIC_RELEASE, __HIP_MEMORY_SCOPE_AGENT);
        }
    } else {
        // =================== layer-1 chain (consumer of x1) ===================
        const f4* pack = pl1;
        #pragma unroll
        for (int i = 0; i < 18; ++i) wlds[t + 512 * i] = pack[t + 512 * i];
        f4 wrA[11], wrB[11];
        #pragma unroll
        for (int g = 0; g < 11; ++g) {
            wrA[g] = pack[(9 + g) * 1024 + j0];
            wrB[g] = pack[(9 + g) * 1024 + j1];
        }
        #pragma unroll
        for (int g = 0; g < 11; ++g)
            asm volatile("" : "+v"(wrA[g]), "+v"(wrB[g]));
        const f4* str = pack + 20 * 1024;

        if (t < 32) { f4 zz = {0.f, 0.f, 0.f, 0.f}; ((f4*)hbuf)[t] = zz; }
        float cst = 0.f, hsum = 0.f;
        __syncthreads();
        const f16* x1b = x1 + (size_t)b * NT * NG;
        f16* houtb = h1 + (size_t)b * NT * NH;
        const unsigned int* pfl = flags + 1024 + b * 16;
        bool dead = false;
        const int u = t >> 1, odd = t & 1;

        f4 pA0[2], pA1[2], pB0[2], pB1[2];
        STREAM_PROLOGUE()

        #pragma unroll 1
        for (int tt = 0; tt < NT; ++tt) {
            if ((tt & 7) == 0) {                  // chunk-grained acquire, one wave spins
                if (t < 64 && !dead) {
                    unsigned int guard = 0;
                    while (__hip_atomic_load(pfl, __ATOMIC_ACQUIRE, __HIP_MEMORY_SCOPE_AGENT)
                           < (unsigned)((tt >> 3) + 1)) {
                        __builtin_amdgcn_s_sleep(8);
                        if (++guard > (1u << 16)) { dead = true; break; }
                    }
                }
                __syncthreads();
            }

            // x1 load issued here, consumed AFTER all dots (latency hidden)
            const f16* xr = x1b + (size_t)tt * NG;
            float x1v0 = (float)xr[j0];
            float x1v1 = (float)xr[j1];
            float a0 = 0.f, a1 = 0.f, a0b = 0.f, a1b = 0.f;

            const f4* hv4 = ((const f4*)hbuf) + (tt & 1) * 32;
            #pragma unroll
            for (int i = 0; i < 9; ++i) DOT8(wlds[i * 1024 + j0], wlds[i * 1024 + j1], hv4[i]);
            STREAM_PHASES(hv4)

            float av = a0 + a0b + x1v0;
            float bv = a1 + a1b + x1v1;
            float fa = __shfl_xor(av, 1, 64);
            float fb = __shfl_xor(bv, 1, 64);
            float gi = odd ? fa : av;
            float gf = odd ? av : fa;
            float gg = odd ? fb : bv;
            float go = odd ? bv : fb;
            float si = 1.f / (1.f + __expf(-gi));
            float sf = 1.f / (1.f + __expf(-gf));
            float so = 1.f / (1.f + __expf(-go));
            float tg = 1.f - 2.f / (__expf(2.f * gg) + 1.f);
            cst = sf * cst + si * tg;
            float th = 1.f - 2.f / (__expf(2.f * cst) + 1.f);
            float hvl = so * th;
            if (!odd) {
                hbuf[(tt & 1) ^ 1][u] = (f16)hvl;
                houtb[(size_t)tt * NH + u] = (f16)hvl;
                hsum += hvl;
            }
            STREAM_PROLOGUE()   // next-step groups 0-3, in flight across barrier
            lbar();             // one light barrier per step
        }
        if (!odd) mmean[b * NH + u] = hsum * (1.f / 512.f);
    }
}

// ---------------- K4a (proven) ----------------
__global__ __launch_bounds__(256)
void k4a(const f16* __restrict__ h1, const float* __restrict__ mmean,
         const float* __restrict__ Wl1, const float* __restrict__ b1,
         const f4* __restrict__ wr1p, float* __restrict__ m1sum,
         float* __restrict__ hh1last)
{
    __shared__ __align__(16) f16 ash[64 * 256];
    __shared__ float msh[256];
    __shared__ float mbase[128];
    __shared__ float red[256];
    const int l = threadIdx.x;
    const int b = blockIdx.x >> 3;
    const int ch = blockIdx.x & 7;

    const f4* src = (const f4*)(h1 + ((size_t)b * 512 + ch * 64) * 256);
    f4* dst = (f4*)ash;
    #pragma unroll
    for (int i = 0; i < 8; ++i) dst[l + 256 * i] = src[l + 256 * i];
    msh[l] = mmean[b * 256 + l];
    __syncthreads();

    if (l < 128) {
        float acc = 0.f;
        if (l < 100) {
            acc = b1[l];
            const float* wrow = Wl1 + l * 256;
            for (int j = 0; j < 256; ++j) acc += msh[j] * wrow[j];
        }
        mbase[l] = acc;
    }
    __syncthreads();

    const int o = l & 127;
    const int th = l >> 7;
    float sumloc = 0.f;
    float last = 0.f;
    #pragma unroll 1
    for (int it = 0; it < 32; ++it) {
        const int tloc = it * 2 + th;
        float acc = mbase[o];
        const f4* arow = (const f4*)(ash + tloc * 256);
        #pragma unroll
        for (int u = 0; u < 32; ++u) {
            F4H av; av.v = arow[u];
            F4H wv; wv.v = wr1p[u * 128 + o];
            #pragma unroll
            for (int p = 0; p < 4; ++p) acc = fdot2(av.h[p], wv.h[p], acc);
        }
        float e = acc > 0.f ? acc : (__expf(acc) - 1.f);
        sumloc += e;
        if (tloc == 63) last = e;
    }
    red[l] = sumloc;
    __syncthreads();
    if (l < 128) {
        float s = red[l] + red[l + 128];
        if (l < 100) atomicAdd(m1sum + b * 128 + l, s);
    }
    if (ch == 7 && th == 1) hh1last[b * 128 + o] = last;
}

// ---------------- K4b: final head (proven) ----------------
__global__ __launch_bounds__(128)
void k4b(const float* __restrict__ m1sum, const float* __restrict__ hh1last,
         const float* __restrict__ Wl2, const float* __restrict__ Wr2,
         const float* __restrict__ b2,
         const float* __restrict__ Wfc1, const float* __restrict__ bfc1,
         const float* __restrict__ Wfc2, const float* __restrict__ bfc2,
         float* __restrict__ out)
{
    __shared__ float m1s[128];
    __shared__ float hl[128];
    __shared__ float s[128];
    __shared__ float zsh[512];
    const int b = blockIdx.x;
    const int l = threadIdx.x;

    m1s[l] = m1sum[b * 128 + l] * (1.f / 512.f);
    hl[l] = hh1last[b * 128 + l];
    __syncthreads();

    {
        float acc = b2[l];
        const float* wl2r = Wl2 + l * 100;
        const float* wr2r = Wr2 + l * 100;
        for (int j = 0; j < 100; ++j) acc += m1s[j] * wl2r[j] + hl[j] * wr2r[j];
        s[l] = acc;
    }
    __syncthreads();

    #pragma unroll 1
    for (int i = 0; i < 4; ++i) {
        const int idx = l + 128 * i;
        const int k = idx >> 6, o = idx & 63;
        const float* w = Wfc1 + (size_t)(k * 64 + o) * 128;
        float a = bfc1[k * 64 + o];
        for (int d = 0; d < 128; ++d) a += s[d] * w[d];
        zsh[idx] = a > 0.f ? a : 0.f;
    }
    __syncthreads();

    #pragma unroll 1
    for (int i = 0; i < 2; ++i) {
        const int idx = l + 128 * i;
        if (idx < 192) {
            const int k = idx / 24, p = idx % 24;
            const float* w = Wfc2 + (size_t)(k * 24 + p) * 64;
            float a = bfc2[k * 24 + p];
            const float* z = zsh + k * 64;
            for (int d = 0; d < 64; ++d) a += z[d] * w[d];
            out[(size_t)(k * 64 + b) * 24 + p] = a;
        }
    }
}

// ---------------- launch ----------------
extern "C" void kernel_launch(void* const* d_in, const int* in_sizes, int n_in,
                              void* d_out, int out_size, void* d_ws, size_t ws_size,
                              hipStream_t stream)
{
    const float* x    = (const float*)d_in[0];
    const float* Wih0 = (const float*)d_in[1];
    const float* Whh0 = (const float*)d_in[2];
    const float* bih0 = (const float*)d_in[3];
    const float* bhh0 = (const float*)d_in[4];
    const float* Wih1 = (const float*)d_in[5];
    const float* Whh1 = (const float*)d_in[6];
    const float* bih1 = (const float*)d_in[7];
    const float* bhh1 = (const float*)d_in[8];
    const float* Wl1  = (const float*)d_in[9];
    const float* Wr1  = (const float*)d_in[10];
    const float* b1   = (const float*)d_in[11];
    const float* Wl2  = (const float*)d_in[12];
    const float* Wr2  = (const float*)d_in[13];
    const float* b2   = (const float*)d_in[14];
    const float* Wfc1 = (const float*)d_in[15];
    const float* bfc1 = (const float*)d_in[16];
    const float* Wfc2 = (const float*)d_in[17];
    const float* bfc2 = (const float*)d_in[18];

    char* ws = (char*)d_ws;
    f16*   h0f   = (f16*)(ws + OFF_H0);
    f16*   x1f   = (f16*)(ws + OFF_X1);
    f16*   h1f   = (f16*)(ws + OFF_H1);
    f4*    pl0   = (f4*)(ws + OFF_PL0);
    f4*    pl1   = (f4*)(ws + OFF_PL1);
    f4*    wih1p = (f4*)(ws + OFF_WIH1);
    h2*    wx0p  = (h2*)(ws + OFF_WX0);
    float* b0c   = (float*)(ws + OFF_B0C);
    float* b1c   = (float*)(ws + OFF_B1C);
    f4*    wr1p  = (f4*)(ws + OFF_WR1);
    float* mm    = (float*)(ws + OFF_MM);
    float* m1s   = (float*)(ws + OFF_M1S);
    float* hhl   = (float*)(ws + OFF_HL);
    unsigned int* flg = (unsigned int*)(ws + OFF_FLG);

    pack_all<<<424, 256, 0, stream>>>(Whh0, Whh1, Wih1, Wih0,
                                      bih0, bhh0, bih1, bhh1, Wr1,
                                      pl0, pl1, wih1p, b0c, b1c, wx0p, wr1p);
    hipMemsetAsync(m1s, 0, 64 * 128 * sizeof(float), stream);
    hipMemsetAsync(flg, 0, 8192, stream);

    // pipelined chain0 -> k2 -> chain1, one launch, 192 co-resident WGs
    mega<<<192, 512, 0, stream>>>(x, pl0, pl1, wih1p, b0c, b1c, wx0p,
                                  h0f, x1f, h1f, mm, flg);

    k4a<<<512, 256, 0, stream>>>(h1f, mm, Wl1, b1, wr1p, m1s, hhl);
    k4b<<<64, 128, 0, stream>>>(m1s, hhl, Wl2, Wr2, b2, Wfc1, bfc1, Wfc2, bfc2, (float*)d_out);
}